// Round 4
// baseline (140.308 us; speedup 1.0000x reference)
//
#include <hip/hip_runtime.h>
#include <math.h>

#define T_STEPS 9
#define D_IN    512
#define HID     64
#define G4      256   // 4*HID
#define BPB     4     // batches per block
#define MROWS   48    // padded tile rows (36 real = BPB*T_STEPS)
#define NCH     8     // K chunks of 64

typedef short  short8 __attribute__((ext_vector_type(8)));
typedef float  f32x4  __attribute__((ext_vector_type(4)));
typedef unsigned int uint;
typedef unsigned short ushort;

// ---------------------------------------------------------------------------
__device__ __forceinline__ ushort f2bf(float f) {
    uint u = __float_as_uint(f);
    u = (u + 0x7FFFu + ((u >> 16) & 1u)) >> 16;   // RNE
    return (ushort)u;
}
__device__ __forceinline__ float fsig(float x) {
    return 1.0f / (1.0f + __expf(-x));
}
__device__ __forceinline__ float ftanh(float x) {
    float t = __expf(-2.0f * fabsf(x));
    float r = (1.0f - t) / (1.0f + t);
    return copysignf(r, x);
}
// packed f32 pair -> one uint holding 2 bf16 (RNE; low16 = cvt(a))
__device__ __forceinline__ uint cvtpk(float a, float b) {
    uint r;
    asm("v_cvt_pk_bf16_f32 %0, %1, %2" : "=v"(r) : "v"(a), "v"(b));
    return r;
}

// ---------------------------------------------------------------------------
// Prepass: weights -> bf16 fragment layouts; coalesced reads AND coalesced
// 16B writes. WxT: [blk(64)][n(256)][j(8)], k = blk*8+j.
// WhT: [kq(8)][n(256)][j(8)].
__global__ __launch_bounds__(256)
void prep_w(const float* __restrict__ kern, ushort* __restrict__ wxT,
            ushort* __restrict__ whT)
{
    const int blk = blockIdx.x;           // 0..63 -> wxT, 64..71 -> whT
    const int n   = threadIdx.x;          // 0..255
    const int krow0 = (blk < 64) ? blk * 8 : 512 + (blk - 64) * 8;
    union { ushort us[8]; short8 v; } o;
    #pragma unroll
    for (int j = 0; j < 8; ++j)
        o.us[j] = f2bf(kern[(size_t)(krow0 + j) * G4 + n]);
    if (blk < 64) *(short8*)&wxT[((size_t)blk * 256 + n) * 8] = o.v;
    else          *(short8*)&whT[((size_t)(blk - 64) * 256 + n) * 8] = o.v;
}

// ---------------------------------------------------------------------------
// Fused LSTM, R12: BPB=4 for 2x grid concurrency (1024 blocks -> 3-4
// blocks/CU vs the old hard 2/CU cap; the 17.9% occupancy was the common
// limiter across all prior phase-1 designs).
//   Phase 1: 8 chunks of K=64. Tile = 48 rows (36 real, rows 36-47 clamp to
//   a real x row -> finite garbage, their C rows are never extracted).
//   Reg-staged: 3 float4/thread/chunk (coalesced), cvt_pk -> ds_write_b64
//   into bf16 chunk tile, swizzle addr = row*64 + ((oct^(row&7))*8) + half*4
//   (write covers all 32 banks; ds_read_b128 fragment reads at the 8-cy
//   floor). Triple-buffered 6KB chunks; stage loads issued 3 chunks ahead;
//   bFb loaded fresh each chunk BEFORE the barrier (latency hides under the
//   barrier wait). No manual vmcnt -> compiler emits exact counted waits.
//   Phase 2, quad-rotation mapping: tile row = s*4+b => step s lives in
//   acc fragment s>>2 at C rows (s&3)*4+r (C row = quad*4+r), so active
//   quad = s&3. h_s is written to sH A-rows ((s+1)&3)*4+r = exactly the
//   rows step s+1's MFMA needs; stale rows feed only discarded C rows.
//   c-state hops to the next quad via __shfl(cst, lane-16). One
//   lgkmcnt(0)+s_barrier per step (no vmcnt drain of out-stores).
__global__ __launch_bounds__(256, 3)
void lstm_fused(const float* __restrict__ x, const ushort* __restrict__ wxT,
                const ushort* __restrict__ whT, const float* __restrict__ bias,
                float* __restrict__ out)
{
    __shared__ __align__(16) ushort sA[3][MROWS * 64];  // 3 x 6 KB bf16 chunks
    __shared__ __align__(16) ushort sH[1024];           // 2 KB [kq(8)][m(16)][j(8)]

    const int t = threadIdx.x;
    const int w = t >> 6, l = t & 63;
    const int lane15 = l & 15, quad = l >> 4;
    const int u = w * 16 + lane15;

    // ---- staging constants: thread t, pass j covers tile row j*16 + (t>>4),
    // k-quad sq = t&15 (16B src, 8B bf16 dst). 48 rows x 16 segs = 768
    // float4 = 3/thread exactly. Tile row = s*4+b -> x row b*9+s; rows
    // 36-47 clamp s to 8 (finite garbage, C rows never consumed).
    const float* xbase = x + (size_t)blockIdx.x * (BPB * T_STEPS * D_IN);
    const int sq = t & 15, ow = sq >> 1, hw = sq & 1;
    int src[3], wad[3];
    #pragma unroll
    for (int j = 0; j < 3; ++j) {
        int row = j * 16 + (t >> 4);
        int b_ = row & 3, s_ = row >> 2;
        if (s_ > 8) s_ = 8;
        src[j] = (b_ * 9 + s_) * 512 + sq * 4;
        wad[j] = row * 64 + ((ow ^ (row & 7)) << 3) + (hw << 2);  // ushorts
    }

    // ---- zero sH (h_{-1} = 0); published by the iter-0 barrier
    if (t < 128) {
        uint4 z = {0u, 0u, 0u, 0u};
        *(uint4*)&sH[t * 8] = z;
    }

    // ---- prologue: chunk0 -> svA, chunk1 -> svB; write chunk0; refill svA
    float4 svA[3], svB[3];
    #pragma unroll
    for (int j = 0; j < 3; ++j) svA[j] = *(const float4*)&xbase[src[j]];
    #pragma unroll
    for (int j = 0; j < 3; ++j) svB[j] = *(const float4*)&xbase[src[j] + 64];
    #pragma unroll
    for (int j = 0; j < 3; ++j) {
        uint2 p;
        p.x = cvtpk(svA[j].x, svA[j].y);
        p.y = cvtpk(svA[j].z, svA[j].w);
        *(uint2*)&sA[0][wad[j]] = p;
    }
    #pragma unroll
    for (int j = 0; j < 3; ++j) svA[j] = *(const float4*)&xbase[src[j] + 128];

    // =============  Phase 1: pipelined K-chunks  ===============
    f32x4 acc[3][4];
    #pragma unroll
    for (int i = 0; i < 3; ++i)
        #pragma unroll
        for (int g = 0; g < 4; ++g)
            acc[i][g] = (f32x4){0.f, 0.f, 0.f, 0.f};

    #pragma unroll
    for (int k = 0; k < NCH; ++k) {
        // (a) Wx fragments for THIS chunk; issued pre-barrier so L2 latency
        //     hides under the barrier wait (no LDS hazard: global->reg)
        short8 bFb[2][4];
        #pragma unroll
        for (int kk = 0; kk < 2; ++kk)
            #pragma unroll
            for (int g = 0; g < 4; ++g)
                bFb[kk][g] = *(const short8*)
                    &wxT[(size_t)(((k * 2 + kk) * 4 + quad) * 256 + g * 64 + u) * 8];
        // (b) write chunk k+1 from reg set (k+1)&1
        if (k < NCH - 1) {
            #pragma unroll
            for (int j = 0; j < 3; ++j) {
                float4 v = ((k + 1) & 1) ? svB[j] : svA[j];
                uint2 p;
                p.x = cvtpk(v.x, v.y);
                p.y = cvtpk(v.z, v.w);
                *(uint2*)&sA[(k + 1) % 3][wad[j]] = p;
            }
        }
        // (c) issue stage loads for chunk k+3 into set (k+3)&1 = (k+1)&1
        //     (freed by (b)); they stay in flight across the barrier
        if (k < NCH - 3) {
            #pragma unroll
            for (int j = 0; j < 3; ++j) {
                float4 v = *(const float4*)&xbase[src[j] + (k + 3) * 64];
                if ((k + 3) & 1) svB[j] = v; else svA[j] = v;
            }
        }
        // fence: own ds_writes drained; raw barrier (no vmcnt drain)
        asm volatile("s_waitcnt lgkmcnt(0)" ::: "memory");
        __builtin_amdgcn_sched_barrier(0);
        __builtin_amdgcn_s_barrier();
        __builtin_amdgcn_sched_barrier(0);
        // (d) compute chunk k: 6x ds_read_b128 (8-cy floor) + 24 MFMA
        #pragma unroll
        for (int kk = 0; kk < 2; ++kk) {
            #pragma unroll
            for (int i = 0; i < 3; ++i) {
                int row = i * 16 + lane15;
                short8 aF = *(const short8*)
                    &sA[k % 3][row * 64 + (((kk * 4 + quad) ^ (row & 7)) << 3)];
                #pragma unroll
                for (int g = 0; g < 4; ++g)
                    acc[i][g] = __builtin_amdgcn_mfma_f32_16x16x32_bf16(
                        aF, bFb[kk][g], acc[i][g], 0, 0, 0);
            }
        }
    }

    // =======================  Phase 2: recurrence  ========================
    short8 whF[4][2];
    #pragma unroll
    for (int g = 0; g < 4; ++g)
        #pragma unroll
        for (int kh = 0; kh < 2; ++kh)
            whF[g][kh] = *(const short8*)
                &whT[(size_t)((kh * 4 + quad) * 256 + g * 64 + u) * 8];

    float bia[4];
    bia[0] = bias[u];
    bia[1] = bias[64 + u];
    bia[2] = bias[128 + u] + 1.0f;       // FORGET_BIAS folded
    bia[3] = bias[192 + u];

    float cst[4] = {0.f, 0.f, 0.f, 0.f};
    const int b0 = blockIdx.x * BPB;

    #pragma unroll                         // static acc[] indices
    for (int s = 0; s < T_STEPS; ++s) {
        const int  i = s >> 2;                 // acc fragment holding step s
        const bool active = (quad == (s & 3)); // C rows (s&3)*4+r
        f32x4 g4[4];
        #pragma unroll
        for (int g = 0; g < 4; ++g)
            #pragma unroll
            for (int r = 0; r < 4; ++r)
                g4[g][r] = acc[i][g][r] + bia[g];

        // h_{s-1} fragments: rows (s&3)*4..+4 hold h_{s-1} (written at step
        // s-1); stale rows feed only discarded C rows (other quads).
        short8 aF[2];
        #pragma unroll
        for (int kh = 0; kh < 2; ++kh)
            aF[kh] = *(const short8*)&sH[((kh * 4 + quad) * 16 + lane15) * 8];

        #pragma unroll
        for (int g = 0; g < 4; ++g)
            #pragma unroll
            for (int kh = 0; kh < 2; ++kh)
                g4[g] = __builtin_amdgcn_mfma_f32_16x16x32_bf16(
                    aF[kh], whF[g][kh], g4[g], 0, 0, 0);

        const int wrow = ((s + 1) & 3) * 4;   // sH rows for h_s = next quad
        #pragma unroll
        for (int r = 0; r < 4; ++r) {
            // c_{s-1} lives in the previous quad (same lane15): src = l-16
            float cp = __shfl(cst[r], (l + 48) & 63);
            if (active) {
                float ii = fsig(g4[0][r]);
                float jj = ftanh(g4[1][r]);
                float ff = fsig(g4[2][r]);
                float oo = fsig(g4[3][r]);
                float c  = ff * cp + ii * jj;
                cst[r] = c;
                float h = oo * ftanh(c);
                out[((size_t)(b0 + r) * T_STEPS + s) * HID + u] = h;
                sH[((u >> 3) * 16 + wrow + r) * 8 + (u & 7)] = f2bf(h);
            }
        }
        // single barrier/step: own ds_writes drained (lgkm), out-stores NOT
        // drained (raw s_barrier, no vmcnt(0)). Write rows are read this
        // step only as stale garbage feeding discarded C rows -> benign.
        asm volatile("s_waitcnt lgkmcnt(0)" ::: "memory");
        __builtin_amdgcn_sched_barrier(0);
        __builtin_amdgcn_s_barrier();
        __builtin_amdgcn_sched_barrier(0);
    }
}

// ---------------------------------------------------------------------------
extern "C" void kernel_launch(void* const* d_in, const int* in_sizes, int n_in,
                              void* d_out, int out_size, void* d_ws, size_t ws_size,
                              hipStream_t stream)
{
    const float* x    = (const float*)d_in[0];
    const float* kern = (const float*)d_in[1];
    const float* bias = (const float*)d_in[2];
    float* out = (float*)d_out;

    const int B = in_sizes[0] / (T_STEPS * D_IN);   // 4096

    ushort* wxT = (ushort*)d_ws;                    // 256 KB
    ushort* whT = (ushort*)((char*)d_ws + 262144);  // 32 KB

    prep_w<<<72, 256, 0, stream>>>(kern, wxT, whT);
    lstm_fused<<<B / BPB, 256, 0, stream>>>(x, wxT, whT, bias, out);
}

// Round 6
// 131.537 us; speedup vs baseline: 1.0667x; 1.0667x over previous
//
#include <hip/hip_runtime.h>
#include <math.h>

#define T_STEPS 9
#define D_IN    512
#define HID     64
#define G4      256   // 4*HID
#define BPB     8     // batches per block
#define NCH     8     // K chunks of 64

typedef short  short8 __attribute__((ext_vector_type(8)));
typedef float  f32x4  __attribute__((ext_vector_type(4)));
typedef unsigned int uint;
typedef unsigned short ushort;

// ---------------------------------------------------------------------------
__device__ __forceinline__ ushort f2bf(float f) {
    uint u = __float_as_uint(f);
    u = (u + 0x7FFFu + ((u >> 16) & 1u)) >> 16;   // RNE
    return (ushort)u;
}
__device__ __forceinline__ float fsig(float x) {
    return 1.0f / (1.0f + __expf(-x));
}
__device__ __forceinline__ float ftanh(float x) {
    float t = __expf(-2.0f * fabsf(x));
    float r = (1.0f - t) / (1.0f + t);
    return copysignf(r, x);
}
// packed f32 pair -> one uint holding 2 bf16 (RNE; low16 = cvt(a))
__device__ __forceinline__ uint cvtpk(float a, float b) {
    uint r;
    asm("v_cvt_pk_bf16_f32 %0, %1, %2" : "=v"(r) : "v"(a), "v"(b));
    return r;
}
// non-temporal 16B load via ext-vector type (the builtin rejects
// HIP_vector_type structs but accepts clang ext-vectors). Keeps the x
// stream out of L2 so WxT/WhT (re-read by every block) stay L2-resident.
__device__ __forceinline__ f32x4 ntload4(const float* p) {
    return __builtin_nontemporal_load((const f32x4*)p);
}

// ---------------------------------------------------------------------------
// Prepass: weights -> bf16 fragment layouts; coalesced reads AND coalesced
// 16B writes. WxT: [blk(64)][n(256)][j(8)], k = blk*8+j.
// WhT: [kq(8)][n(256)][j(8)].
__global__ __launch_bounds__(256)
void prep_w(const float* __restrict__ kern, ushort* __restrict__ wxT,
            ushort* __restrict__ whT)
{
    const int blk = blockIdx.x;           // 0..63 -> wxT, 64..71 -> whT
    const int n   = threadIdx.x;          // 0..255
    const int krow0 = (blk < 64) ? blk * 8 : 512 + (blk - 64) * 8;
    union { ushort us[8]; short8 v; } o;
    #pragma unroll
    for (int j = 0; j < 8; ++j)
        o.us[j] = f2bf(kern[(size_t)(krow0 + j) * G4 + n]);
    if (blk < 64) *(short8*)&wxT[((size_t)blk * 256 + n) * 8] = o.v;
    else          *(short8*)&whT[((size_t)(blk - 64) * 256 + n) * 8] = o.v;
}

// ---------------------------------------------------------------------------
// Fused LSTM, R14 = R13 with the nt-load routed through an ext-vector type.
//   Theory: all prior variants (45-49us) are bound on WEIGHT RE-READ
//   bandwidth: 512 blocks x 288KB WxT/WhT = 147MB served from L3 because
//   the per-XCD x stream (9.4MB through a 4MB L2) evicts the weight lines.
//   R12's 2x-blocks -> 2x-time confirmed traffic ∝ time. nt x loads keep
//   L2 clean so weights are served at L2 BW.
//   Phase 1: 8 chunks of K=64, reg-staged (load float4 -> cvt_pk ->
//   ds_write_b64), bf16 chunk tile, swizzle addr = row*64 + ((oct^(row&7))*8)
//   + half*4 (write covers 32 banks; ds_read_b128 frag reads at 8-cy floor).
//   Triple-buffered 10KB chunks; stage loads 3 chunks ahead; bFb prefetched
//   1 chunk ahead. No manual vmcnt (compiler emits exact counted waits).
//   One lgkmcnt(0)+s_barrier per chunk.
//   Phase 2: parity recurrence, one raw barrier/step.
__global__ __launch_bounds__(256, 2)
void lstm_fused(const float* __restrict__ x, const ushort* __restrict__ wxT,
                const ushort* __restrict__ whT, const float* __restrict__ bias,
                float* __restrict__ out)
{
    __shared__ __align__(16) ushort sA[3][80 * 64];  // 3 x 10 KB bf16 chunks
    __shared__ __align__(16) ushort sH[1024];        // 2 KB [kq(8)][m(16)][j(8)]

    const int t = threadIdx.x;
    const int w = t >> 6, l = t & 63;
    const int lane15 = l & 15, quad = l >> 4;
    const int u = w * 16 + lane15;

    // ---- staging constants: thread t, pass j covers chunk-tile row
    // row = j*16 + (t>>4), k-quad sq = t&15 (4 f32 = 16B src, 8B bf16 dst).
    // Tile row = s*8+b -> x row b*9+s; rows 72-79 clamp to s=8 (garbage ok:
    // their C rows are never consumed).
    const float* xbase = x + (size_t)blockIdx.x * (72 * D_IN);
    const int sq = t & 15, ow = sq >> 1, hw = sq & 1;
    int src[5], wad[5];
    #pragma unroll
    for (int j = 0; j < 5; ++j) {
        int row = j * 16 + (t >> 4);
        int b_ = row & 7, s_ = row >> 3;
        if (s_ > 8) s_ = 8;
        src[j] = (b_ * 9 + s_) * 512 + sq * 4;
        wad[j] = row * 64 + ((ow ^ (row & 7)) << 3) + (hw << 2);  // ushorts
    }

    // ---- zero sH (h_0 = 0); visible to all waves after iter-0 barrier
    if (t < 128) {
        uint4 z = {0u, 0u, 0u, 0u};
        *(uint4*)&sH[t * 8] = z;
    }

    // ---- prologue: S0 -> svA, S1 -> svB, bFb chunk0 -> set0
    f32x4 svA[5], svB[5];
    #pragma unroll
    for (int j = 0; j < 5; ++j) svA[j] = ntload4(&xbase[src[j]]);
    #pragma unroll
    for (int j = 0; j < 5; ++j) svB[j] = ntload4(&xbase[src[j] + 64]);

    short8 bFb[2][2][4];
    #pragma unroll
    for (int kk = 0; kk < 2; ++kk)
        #pragma unroll
        for (int g = 0; g < 4; ++g)
            bFb[0][kk][g] = *(const short8*)
                &wxT[(size_t)((kk * 4 + quad) * 256 + g * 64 + u) * 8];

    // write chunk 0 (consumes svA), then refill svA with S2
    #pragma unroll
    for (int j = 0; j < 5; ++j) {
        uint2 p;
        p.x = cvtpk(svA[j][0], svA[j][1]);
        p.y = cvtpk(svA[j][2], svA[j][3]);
        *(uint2*)&sA[0][wad[j]] = p;
    }
    #pragma unroll
    for (int j = 0; j < 5; ++j) svA[j] = ntload4(&xbase[src[j] + 128]);

    // =============  Phase 1: pipelined K-chunks  ===============
    f32x4 acc[5][4];
    #pragma unroll
    for (int i = 0; i < 5; ++i)
        #pragma unroll
        for (int g = 0; g < 4; ++g)
            acc[i][g] = (f32x4){0.f, 0.f, 0.f, 0.f};

    #pragma unroll
    for (int k = 0; k < NCH; ++k) {
        // (b) write chunk k+1 from reg set (k+1)&1
        if (k < NCH - 1) {
            #pragma unroll
            for (int j = 0; j < 5; ++j) {
                f32x4 v = ((k + 1) & 1) ? svB[j] : svA[j];
                uint2 p;
                p.x = cvtpk(v[0], v[1]);
                p.y = cvtpk(v[2], v[3]);
                *(uint2*)&sA[(k + 1) % 3][wad[j]] = p;
            }
        }
        // (c1) prefetch bFb for chunk k+1 into set (k+1)&1 (L2-resident now)
        if (k < NCH - 1) {
            #pragma unroll
            for (int kk = 0; kk < 2; ++kk)
                #pragma unroll
                for (int g = 0; g < 4; ++g)
                    bFb[(k + 1) & 1][kk][g] = *(const short8*)
                        &wxT[(size_t)((((k + 1) * 2 + kk) * 4 + quad) * 256
                                      + g * 64 + u) * 8];
        }
        // (c2) issue stage loads for chunk k+3 into set (k+3)&1 = (k+1)&1
        //      (freed by (b) above); they stay in flight across the barrier
        if (k < NCH - 3) {
            #pragma unroll
            for (int j = 0; j < 5; ++j) {
                f32x4 v = ntload4(&xbase[src[j] + (k + 3) * 64]);
                if ((k + 3) & 1) svB[j] = v; else svA[j] = v;
            }
        }
        // fence: own ds_writes drained; raw barrier (no vmcnt drain)
        asm volatile("s_waitcnt lgkmcnt(0)" ::: "memory");
        __builtin_amdgcn_sched_barrier(0);
        __builtin_amdgcn_s_barrier();
        __builtin_amdgcn_sched_barrier(0);
        // (d) compute chunk k: 10x ds_read_b128 (conflict-free) + 40 MFMA
        #pragma unroll
        for (int kk = 0; kk < 2; ++kk) {
            #pragma unroll
            for (int i = 0; i < 5; ++i) {
                int row = i * 16 + lane15;
                short8 aF = *(const short8*)
                    &sA[k % 3][row * 64 + (((kk * 4 + quad) ^ (row & 7)) << 3)];
                #pragma unroll
                for (int g = 0; g < 4; ++g)
                    acc[i][g] = __builtin_amdgcn_mfma_f32_16x16x32_bf16(
                        aF, bFb[k & 1][kk][g], acc[i][g], 0, 0, 0);
            }
        }
    }

    // =======================  Phase 2: recurrence  ========================
    short8 whF[4][2];
    #pragma unroll
    for (int g = 0; g < 4; ++g)
        #pragma unroll
        for (int kh = 0; kh < 2; ++kh)
            whF[g][kh] = *(const short8*)
                &whT[(size_t)((kh * 4 + quad) * 256 + g * 64 + u) * 8];

    float bia[4];
    bia[0] = bias[u];
    bia[1] = bias[64 + u];
    bia[2] = bias[128 + u] + 1.0f;       // FORGET_BIAS folded
    bia[3] = bias[192 + u];

    float cst[4] = {0.f, 0.f, 0.f, 0.f};
    const int b0 = blockIdx.x * BPB;

    #pragma unroll                         // static acc[] indices
    for (int s = 0; s < T_STEPS; ++s) {
        const int  i = s >> 1;
        const int  p = s & 1;
        const bool active = ((quad >> 1) == p);   // quads {2p,2p+1} hold step s
        const int  bofs = (quad & 1) * 4;         // batch = bofs + r

        f32x4 g4[4];
        #pragma unroll
        for (int g = 0; g < 4; ++g)
            #pragma unroll
            for (int r = 0; r < 4; ++r)
                g4[g][r] = acc[i][g][r] + bia[g];

        // h_{s-1} fragments: active C rows (8p..8p+7) depend only on sH rows
        // holding h_{s-1}; the other half feeds inactive C rows only.
        short8 aF[2];
        #pragma unroll
        for (int kh = 0; kh < 2; ++kh)
            aF[kh] = *(const short8*)&sH[((kh * 4 + quad) * 16 + lane15) * 8];

        #pragma unroll
        for (int g = 0; g < 4; ++g)
            #pragma unroll
            for (int kh = 0; kh < 2; ++kh)
                g4[g] = __builtin_amdgcn_mfma_f32_16x16x32_bf16(
                    aF[kh], whF[g][kh], g4[g], 0, 0, 0);

        const int wrow = 8 * ((s + 1) & 1);   // rows for h_s = next parity
        #pragma unroll
        for (int r = 0; r < 4; ++r) {
            float cp = __shfl_xor(cst[r], 32);   // partner quad's c_{s-1}
            if (active) {
                float ii = fsig(g4[0][r]);
                float jj = ftanh(g4[1][r]);
                float ff = fsig(g4[2][r]);
                float oo = fsig(g4[3][r]);
                float c  = ff * cp + ii * jj;
                cst[r] = c;
                float h = oo * ftanh(c);
                int bb = bofs + r;
                __builtin_nontemporal_store(
                    h, &out[((size_t)(b0 + bb) * T_STEPS + s) * HID + u]);
                sH[((u >> 3) * 16 + wrow + bb) * 8 + (u & 7)] = f2bf(h);
            }
        }
        // single barrier/step: own ds_writes drained (lgkm), out-stores NOT
        // drained (raw s_barrier, no vmcnt(0))
        asm volatile("s_waitcnt lgkmcnt(0)" ::: "memory");
        __builtin_amdgcn_sched_barrier(0);
        __builtin_amdgcn_s_barrier();
        __builtin_amdgcn_sched_barrier(0);
    }
}

// ---------------------------------------------------------------------------
extern "C" void kernel_launch(void* const* d_in, const int* in_sizes, int n_in,
                              void* d_out, int out_size, void* d_ws, size_t ws_size,
                              hipStream_t stream)
{
    const float* x    = (const float*)d_in[0];
    const float* kern = (const float*)d_in[1];
    const float* bias = (const float*)d_in[2];
    float* out = (float*)d_out;

    const int B = in_sizes[0] / (T_STEPS * D_IN);   // 4096

    ushort* wxT = (ushort*)d_ws;                    // 256 KB
    ushort* whT = (ushort*)((char*)d_ws + 262144);  // 32 KB

    prep_w<<<72, 256, 0, stream>>>(kern, wxT, whT);
    lstm_fused<<<B / BPB, 256, 0, stream>>>(x, wxT, whT, bias, out);
}

// Round 7
// 128.477 us; speedup vs baseline: 1.0921x; 1.0238x over previous
//
#include <hip/hip_runtime.h>
#include <math.h>

#define T_STEPS 9
#define D_IN    512
#define HID     64
#define G4      256   // 4*HID
#define BPB     16    // batches per block
#define TROWS   160   // padded tile rows (144 real = BPB*T_STEPS)
#define NFRAG   9     // 16-row fragments actually computed (144 real rows)
#define NCH     8     // K chunks of 64

typedef short  short8 __attribute__((ext_vector_type(8)));
typedef float  f32x4  __attribute__((ext_vector_type(4)));
typedef unsigned int uint;
typedef unsigned short ushort;

// ---------------------------------------------------------------------------
__device__ __forceinline__ ushort f2bf(float f) {
    uint u = __float_as_uint(f);
    u = (u + 0x7FFFu + ((u >> 16) & 1u)) >> 16;   // RNE
    return (ushort)u;
}
__device__ __forceinline__ float fsig(float x) {
    return 1.0f / (1.0f + __expf(-x));
}
__device__ __forceinline__ float ftanh(float x) {
    float t = __expf(-2.0f * fabsf(x));
    float r = (1.0f - t) / (1.0f + t);
    return copysignf(r, x);
}
// packed f32 pair -> one uint holding 2 bf16 (RNE; low16 = cvt(a))
__device__ __forceinline__ uint cvtpk(float a, float b) {
    uint r;
    asm("v_cvt_pk_bf16_f32 %0, %1, %2" : "=v"(r) : "v"(a), "v"(b));
    return r;
}
// non-temporal 16B load (ext-vector type; builtin rejects HIP_vector_type)
__device__ __forceinline__ f32x4 ntload4(const float* p) {
    return __builtin_nontemporal_load((const f32x4*)p);
}

// ---------------------------------------------------------------------------
// Prepass: weights -> bf16 fragment layouts; coalesced reads AND coalesced
// 16B writes. WxT: [blk(64)][n(256)][j(8)], k = blk*8+j.
// WhT: [kq(8)][n(256)][j(8)].
__global__ __launch_bounds__(256)
void prep_w(const float* __restrict__ kern, ushort* __restrict__ wxT,
            ushort* __restrict__ whT)
{
    const int blk = blockIdx.x;           // 0..63 -> wxT, 64..71 -> whT
    const int n   = threadIdx.x;          // 0..255
    const int krow0 = (blk < 64) ? blk * 8 : 512 + (blk - 64) * 8;
    union { ushort us[8]; short8 v; } o;
    #pragma unroll
    for (int j = 0; j < 8; ++j)
        o.us[j] = f2bf(kern[(size_t)(krow0 + j) * G4 + n]);
    if (blk < 64) *(short8*)&wxT[((size_t)blk * 256 + n) * 8] = o.v;
    else          *(short8*)&whT[((size_t)(blk - 64) * 256 + n) * 8] = o.v;
}

// ---------------------------------------------------------------------------
// Fused LSTM, R15: weight-traffic-halving restructure (H1 test at constant
// parallelism). 512-thread blocks, BPB=16, grid 256: still 2 waves/SIMD and
// 2048 waves total, but each wave covers 32 gate-cols x 144 rows, so per-wave
// Wx reads halve -> 147 MB -> 72 MB chip-wide.
//   Gate split: wave pair (2v, 2v+1) owns units un = v*16+lane15;
//   even wave: cols un / 64+un (i,j); odd wave: 128+un / 192+un (f,o).
//   Phase 1: 8 chunks of K=64, reg-staged (ntload float4 -> cvt_pk ->
//   ds_write_b64), bf16 chunk tile [row(160)][k(64)] with verified swizzle
//   addr = row*64 + ((oct^(row&7))*8) + half*4. Triple-buffered 20KB chunks,
//   stage 3 ahead, bFb 1 ahead, no manual vmcnt, one lgkm0+s_barrier/chunk.
//   Tile row = s*16+b (b=row&15, s=row>>4); frag i = step i directly
//   (C rows = batch = quad*4+r, C cols = lane15 ✓). Rows 144-159 staged
//   (clamped source) but never read (frag 9 skipped).
//   Phase 2: per step s: all waves MFMA h_{s-1}·Wh into their gate pair;
//   even computes a = sig(i)*tanh(j) -> aX[b][un]; barrier; odd does
//   c = sig(f+1)*c + a, h = sig(o)*tanh(c), writes out + sH; barrier.
//   sH single-buffered: all aF reads drain before barrier 1, writes after.
__global__ __launch_bounds__(512, 2)
void lstm_fused(const float* __restrict__ x, const ushort* __restrict__ wxT,
                const ushort* __restrict__ whT, const float* __restrict__ bias,
                float* __restrict__ out)
{
    __shared__ __align__(16) ushort sA[3][TROWS * 64];  // 3 x 20 KB bf16 chunks
    __shared__ __align__(16) ushort sH[1024];           // 2 KB [kq(8)][m(16)][j(8)]
    __shared__ __align__(16) float  aX[16 * 64];        // 4 KB exchange a[b][un]

    const int t = threadIdx.x;
    const int w = t >> 6, l = t & 63;
    const int lane15 = l & 15, quad = l >> 4;
    const int un = (w >> 1) * 16 + lane15;   // unit col within 64
    const int nb = (w & 1) * 128;            // 0 -> (i,j) cols; 128 -> (f,o)

    // ---- staging constants: pass j covers row j*32 + (t>>4); sq = t&15.
    // 160 rows x 16 segs = 2560 float4 = 5/thread. Tile row = s*16+b ->
    // x row b*9+s; rows 144-159 clamp s to 8 (staged, never read).
    const float* xbase = x + (size_t)blockIdx.x * (BPB * T_STEPS * D_IN);
    const int sq = t & 15, ow = sq >> 1, hw = sq & 1;
    int src[5], wad[5];
    #pragma unroll
    for (int j = 0; j < 5; ++j) {
        int row = j * 32 + (t >> 4);
        int b_ = row & 15, s_ = row >> 4;
        if (s_ > 8) s_ = 8;
        src[j] = (b_ * 9 + s_) * 512 + sq * 4;
        wad[j] = row * 64 + ((ow ^ (row & 7)) << 3) + (hw << 2);  // ushorts
    }

    // ---- zero sH (h_{-1} = 0)
    if (t < 128) {
        uint4 z = {0u, 0u, 0u, 0u};
        *(uint4*)&sH[t * 8] = z;
    }

    // ---- prologue: S0 -> svA, S1 -> svB, bFb chunk0 -> set0
    f32x4 svA[5], svB[5];
    #pragma unroll
    for (int j = 0; j < 5; ++j) svA[j] = ntload4(&xbase[src[j]]);
    #pragma unroll
    for (int j = 0; j < 5; ++j) svB[j] = ntload4(&xbase[src[j] + 64]);

    short8 bFb[2][2][2];   // [set][kk][g]
    #pragma unroll
    for (int kk = 0; kk < 2; ++kk)
        #pragma unroll
        for (int g = 0; g < 2; ++g)
            bFb[0][kk][g] = *(const short8*)
                &wxT[(size_t)((kk * 4 + quad) * 256 + nb + g * 64 + un) * 8];

    // write chunk 0 (consumes svA), then refill svA with S2
    #pragma unroll
    for (int j = 0; j < 5; ++j) {
        uint2 p;
        p.x = cvtpk(svA[j][0], svA[j][1]);
        p.y = cvtpk(svA[j][2], svA[j][3]);
        *(uint2*)&sA[0][wad[j]] = p;
    }
    #pragma unroll
    for (int j = 0; j < 5; ++j) svA[j] = ntload4(&xbase[src[j] + 128]);

    // =============  Phase 1: pipelined K-chunks  ===============
    f32x4 acc[NFRAG][2];
    #pragma unroll
    for (int i = 0; i < NFRAG; ++i)
        #pragma unroll
        for (int g = 0; g < 2; ++g)
            acc[i][g] = (f32x4){0.f, 0.f, 0.f, 0.f};

    #pragma unroll
    for (int k = 0; k < NCH; ++k) {
        // (b) write chunk k+1 from reg set (k+1)&1
        if (k < NCH - 1) {
            #pragma unroll
            for (int j = 0; j < 5; ++j) {
                f32x4 v = ((k + 1) & 1) ? svB[j] : svA[j];
                uint2 p;
                p.x = cvtpk(v[0], v[1]);
                p.y = cvtpk(v[2], v[3]);
                *(uint2*)&sA[(k + 1) % 3][wad[j]] = p;
            }
        }
        // (c1) prefetch bFb for chunk k+1 into set (k+1)&1
        if (k < NCH - 1) {
            #pragma unroll
            for (int kk = 0; kk < 2; ++kk)
                #pragma unroll
                for (int g = 0; g < 2; ++g)
                    bFb[(k + 1) & 1][kk][g] = *(const short8*)
                        &wxT[(size_t)((((k + 1) * 2 + kk) * 4 + quad) * 256
                                      + nb + g * 64 + un) * 8];
        }
        // (c2) issue stage loads for chunk k+3 into set (k+1)&1 (freed by b)
        if (k < NCH - 3) {
            #pragma unroll
            for (int j = 0; j < 5; ++j) {
                f32x4 v = ntload4(&xbase[src[j] + (k + 3) * 64]);
                if ((k + 3) & 1) svB[j] = v; else svA[j] = v;
            }
        }
        // fence: own ds_writes drained; raw barrier (no vmcnt drain)
        asm volatile("s_waitcnt lgkmcnt(0)" ::: "memory");
        __builtin_amdgcn_sched_barrier(0);
        __builtin_amdgcn_s_barrier();
        __builtin_amdgcn_sched_barrier(0);
        // (d) compute chunk k: 18x ds_read_b128 + 36 MFMA (frags 0..8)
        #pragma unroll
        for (int kk = 0; kk < 2; ++kk) {
            #pragma unroll
            for (int i = 0; i < NFRAG; ++i) {
                int row = i * 16 + lane15;
                short8 aF = *(const short8*)
                    &sA[k % 3][row * 64 + (((kk * 4 + quad) ^ (row & 7)) << 3)];
                acc[i][0] = __builtin_amdgcn_mfma_f32_16x16x32_bf16(
                    aF, bFb[k & 1][kk][0], acc[i][0], 0, 0, 0);
                acc[i][1] = __builtin_amdgcn_mfma_f32_16x16x32_bf16(
                    aF, bFb[k & 1][kk][1], acc[i][1], 0, 0, 0);
            }
        }
    }

    // =======================  Phase 2: recurrence  ========================
    short8 whF[2][2];   // [g][kh]
    #pragma unroll
    for (int g = 0; g < 2; ++g)
        #pragma unroll
        for (int kh = 0; kh < 2; ++kh)
            whF[g][kh] = *(const short8*)
                &whT[(size_t)((kh * 4 + quad) * 256 + nb + g * 64 + un) * 8];

    const bool oddw = (w & 1) != 0;
    // even: g0 = i-gate (bias), g1 = j-gate; odd: g0 = f (+FORGET_BIAS), g1 = o
    float bia0 = bias[nb + un] + (oddw ? 1.0f : 0.0f);
    float bia1 = bias[nb + 64 + un];

    float cst[4] = {0.f, 0.f, 0.f, 0.f};     // odd waves: c for batch quad*4+r
    const int b0 = blockIdx.x * BPB;

    #pragma unroll                             // static acc[] indices
    for (int s = 0; s < T_STEPS; ++s) {
        f32x4 g0, g1;
        #pragma unroll
        for (int r = 0; r < 4; ++r) {
            g0[r] = acc[s][0][r] + bia0;
            g1[r] = acc[s][1][r] + bia1;
        }

        // h_{s-1} fragment (16 batches x 64 k)
        short8 aF[2];
        #pragma unroll
        for (int kh = 0; kh < 2; ++kh)
            aF[kh] = *(const short8*)&sH[((kh * 4 + quad) * 16 + lane15) * 8];

        #pragma unroll
        for (int kh = 0; kh < 2; ++kh) {
            g0 = __builtin_amdgcn_mfma_f32_16x16x32_bf16(aF[kh], whF[0][kh], g0, 0, 0, 0);
            g1 = __builtin_amdgcn_mfma_f32_16x16x32_bf16(aF[kh], whF[1][kh], g1, 0, 0, 0);
        }

        if (!oddw) {   // even: a = sig(i)*tanh(j) for batch quad*4+r, unit un
            #pragma unroll
            for (int r = 0; r < 4; ++r)
                aX[(quad * 4 + r) * 64 + un] = fsig(g0[r]) * ftanh(g1[r]);
        }
        // barrier 1: aX visible; all aF reads drained -> sH safely writable
        asm volatile("s_waitcnt lgkmcnt(0)" ::: "memory");
        __builtin_amdgcn_sched_barrier(0);
        __builtin_amdgcn_s_barrier();
        __builtin_amdgcn_sched_barrier(0);

        if (oddw) {    // odd: c/h update, out + sH writes
            #pragma unroll
            for (int r = 0; r < 4; ++r) {
                float a = aX[(quad * 4 + r) * 64 + un];
                float c = fsig(g0[r]) * cst[r] + a;
                cst[r] = c;
                float h = fsig(g1[r]) * ftanh(c);
                int bb = quad * 4 + r;
                __builtin_nontemporal_store(
                    h, &out[((size_t)(b0 + bb) * T_STEPS + s) * HID + un]);
                sH[((un >> 3) * 16 + bb) * 8 + (un & 7)] = f2bf(h);
            }
        }
        // barrier 2: h_s visible; aX consumed -> writable next step
        asm volatile("s_waitcnt lgkmcnt(0)" ::: "memory");
        __builtin_amdgcn_sched_barrier(0);
        __builtin_amdgcn_s_barrier();
        __builtin_amdgcn_sched_barrier(0);
    }
}

// ---------------------------------------------------------------------------
extern "C" void kernel_launch(void* const* d_in, const int* in_sizes, int n_in,
                              void* d_out, int out_size, void* d_ws, size_t ws_size,
                              hipStream_t stream)
{
    const float* x    = (const float*)d_in[0];
    const float* kern = (const float*)d_in[1];
    const float* bias = (const float*)d_in[2];
    float* out = (float*)d_out;

    const int B = in_sizes[0] / (T_STEPS * D_IN);   // 4096

    ushort* wxT = (ushort*)d_ws;                    // 256 KB
    ushort* whT = (ushort*)((char*)d_ws + 262144);  // 32 KB

    prep_w<<<72, 256, 0, stream>>>(kern, wxT, whT);
    lstm_fused<<<B / BPB, 512, 0, stream>>>(x, wxT, whT, bias, out);
}